// Round 2
// baseline (90.670 us; speedup 1.0000x reference)
//
#include <hip/hip_runtime.h>
#include <math.h>

// Problem constants (fixed by the reference setup_inputs)
constexpr int B = 4;
constexpr int N = 8192;
constexpr int M = 8192;
constexpr int NPTS = B * N;   // 32768 xyz1 points
constexpr int MPTS = B * M;   // 32768 xyz2 points

constexpr int TPB = 256;                  // threads per block (main)
constexpr int PB  = 8;                    // xyz1 points per thread
constexpr int PTS_PER_BLOCK = TPB * PB;   // 2048
constexpr int NB1 = N / PTS_PER_BLOCK;    // 4 point-blocks per batch
constexpr int MC  = 64;                   // chunks over M
constexpr int CHUNK = M / MC;             // 128 xyz2 points per chunk

constexpr int RB = 128;                   // reduce kernel blocks

typedef float v2f __attribute__((ext_vector_type(2)));

// ---------------------------------------------------------------------------
// Main O(N*M) kernel. Block = (mc, pb, b). Stages its own q-chunk
// (-2x,-2y,-2z,|p|^2) into LDS as SoA float arrays (broadcast reads,
// conflict-free), then for PB register-resident xyz1 points runs the packed
// inner loop: per 2 q-points per xyz1-point: 3 v_pk_fma_f32 + 1 v_min3_f32.
// Writes per-chunk partial min-d2 to ws (pure stores — no init, no atomics).
// ---------------------------------------------------------------------------
__global__ __launch_bounds__(TPB, 4) void chamfer_min_kernel(
    const float* __restrict__ xyz1, const float* __restrict__ xyz2,
    float* __restrict__ part) {
  __shared__ float lqx[CHUNK], lqy[CHUNK], lqz[CHUNK], lqw[CHUNK];

  const int t  = threadIdx.x;
  const int mc = blockIdx.x;  // M-chunk      0..MC-1
  const int pb = blockIdx.y;  // point-block  0..NB1-1
  const int b  = blockIdx.z;  // batch        0..B-1

  // Stage q chunk: thread k (k < CHUNK) computes one xyz2 point.
  if (t < CHUNK) {
    int gi = b * M + mc * CHUNK + t;
    float x = xyz2[3 * gi + 0];
    float y = xyz2[3 * gi + 1];
    float z = xyz2[3 * gi + 2];
    lqx[t] = -2.0f * x;
    lqy[t] = -2.0f * y;
    lqz[t] = -2.0f * z;
    lqw[t] = fmaf(x, x, fmaf(y, y, z * z));
  }

  // Load this thread's PB xyz1 points as broadcast pairs (both halves equal)
  v2f x1b[PB], y1b[PB], z1b[PB];
  float smin[PB];
  const int base1 = b * N + pb * PTS_PER_BLOCK + t;
#pragma unroll
  for (int p = 0; p < PB; ++p) {
    int idx = base1 + p * TPB;
    float x = xyz1[3 * idx + 0];
    float y = xyz1[3 * idx + 1];
    float z = xyz1[3 * idx + 2];
    x1b[p] = (v2f){x, x};
    y1b[p] = (v2f){y, y};
    z1b[p] = (v2f){z, z};
    smin[p] = INFINITY;
  }
  __syncthreads();

  // Inner loop: 4 q-points per iteration (one ds_read_b128 per component),
  // processed as two packed j-pairs.
#pragma unroll 4
  for (int j4 = 0; j4 < CHUNK / 4; ++j4) {
    float4 vx = *(const float4*)&lqx[4 * j4];
    float4 vy = *(const float4*)&lqy[4 * j4];
    float4 vz = *(const float4*)&lqz[4 * j4];
    float4 vw = *(const float4*)&lqw[4 * j4];

    v2f px0 = (v2f){vx.x, vx.y}, px1 = (v2f){vx.z, vx.w};
    v2f py0 = (v2f){vy.x, vy.y}, py1 = (v2f){vy.z, vy.w};
    v2f pz0 = (v2f){vz.x, vz.y}, pz1 = (v2f){vz.z, vz.w};
    v2f pw0 = (v2f){vw.x, vw.y}, pw1 = (v2f){vw.z, vw.w};

#pragma unroll
    for (int p = 0; p < PB; ++p) {
      v2f s0 = __builtin_elementwise_fma(
          x1b[p], px0,
          __builtin_elementwise_fma(
              y1b[p], py0, __builtin_elementwise_fma(z1b[p], pz0, pw0)));
      smin[p] = fminf(fminf(s0.x, s0.y), smin[p]);
      v2f s1 = __builtin_elementwise_fma(
          x1b[p], px1,
          __builtin_elementwise_fma(
              y1b[p], py1, __builtin_elementwise_fma(z1b[p], pz1, pw1)));
      smin[p] = fminf(fminf(s1.x, s1.y), smin[p]);
    }
  }

  // Epilogue: d2 = max(|p1|^2 + smin, 0); store per-chunk partial (coalesced).
#pragma unroll
  for (int p = 0; p < PB; ++p) {
    int idx = base1 + p * TPB;
    float x = x1b[p].x, y = y1b[p].x, z = z1b[p].x;
    float n2 = fmaf(x, x, fmaf(y, y, z * z));
    float d2 = fmaxf(n2 + smin[p], 0.0f);
    part[(size_t)mc * NPTS + idx] = d2;
  }
}

// ---------------------------------------------------------------------------
// Reduce: per xyz1 point, min over MC chunk-partials; d = sqrt; weighted
// block-level partial sums of (d*w, w) written to ws (no atomics, no init).
// ---------------------------------------------------------------------------
__global__ __launch_bounds__(TPB) void reduce_kernel(
    const float* __restrict__ part, const float* __restrict__ w,
    float* __restrict__ pnum, float* __restrict__ pden) {
  int i = blockIdx.x * TPB + threadIdx.x;  // point 0..NPTS-1

  // 4-way partial mins for ILP over the MC strided loads (coalesced per mc)
  float m0 = INFINITY, m1 = INFINITY, m2 = INFINITY, m3 = INFINITY;
#pragma unroll
  for (int mc = 0; mc < MC; mc += 4) {
    m0 = fminf(m0, part[(size_t)(mc + 0) * NPTS + i]);
    m1 = fminf(m1, part[(size_t)(mc + 1) * NPTS + i]);
    m2 = fminf(m2, part[(size_t)(mc + 2) * NPTS + i]);
    m3 = fminf(m3, part[(size_t)(mc + 3) * NPTS + i]);
  }
  float d  = sqrtf(fminf(fminf(m0, m1), fminf(m2, m3)));
  float wi = w[i];
  float num = d * wi;
  float den = wi;

#pragma unroll
  for (int off = 32; off > 0; off >>= 1) {
    num += __shfl_down(num, off, 64);
    den += __shfl_down(den, off, 64);
  }

  __shared__ float snum[TPB / 64], sden[TPB / 64];
  int wid  = threadIdx.x >> 6;
  int lane = threadIdx.x & 63;
  if (lane == 0) { snum[wid] = num; sden[wid] = den; }
  __syncthreads();
  if (threadIdx.x == 0) {
    float a = 0.0f, c = 0.0f;
#pragma unroll
    for (int k = 0; k < TPB / 64; ++k) { a += snum[k]; c += sden[k]; }
    pnum[blockIdx.x] = a;
    pden[blockIdx.x] = c;
  }
}

// ---------------------------------------------------------------------------
// Finalize: sum RB block-partials, divide. One block of 128 threads.
// ---------------------------------------------------------------------------
__global__ __launch_bounds__(RB) void finalize_kernel(
    const float* __restrict__ pnum, const float* __restrict__ pden,
    float* __restrict__ out) {
  int t = threadIdx.x;
  float num = pnum[t];
  float den = pden[t];
#pragma unroll
  for (int off = 32; off > 0; off >>= 1) {
    num += __shfl_down(num, off, 64);
    den += __shfl_down(den, off, 64);
  }
  __shared__ float sn[2], sd[2];
  if ((t & 63) == 0) { sn[t >> 6] = num; sd[t >> 6] = den; }
  __syncthreads();
  if (t == 0) out[0] = (sn[0] + sn[1]) / (sd[0] + sd[1]);
}

// ---------------------------------------------------------------------------
extern "C" void kernel_launch(void* const* d_in, const int* in_sizes, int n_in,
                              void* d_out, int out_size, void* d_ws,
                              size_t ws_size, hipStream_t stream) {
  const float* xyz1 = (const float*)d_in[0];  // [B,N,3]
  const float* xyz2 = (const float*)d_in[1];  // [B,M,3]
  const float* wts  = (const float*)d_in[2];  // [B,N]
  float* out = (float*)d_out;

  char* ws = (char*)d_ws;
  float* part = (float*)ws;  // MC * NPTS floats = 8 MB
  float* pnum = (float*)(ws + (size_t)MC * NPTS * sizeof(float));
  float* pden = pnum + RB;

  hipLaunchKernelGGL(chamfer_min_kernel, dim3(MC, NB1, B), dim3(TPB), 0,
                     stream, xyz1, xyz2, part);
  hipLaunchKernelGGL(reduce_kernel, dim3(NPTS / TPB), dim3(TPB), 0, stream,
                     part, wts, pnum, pden);
  hipLaunchKernelGGL(finalize_kernel, dim3(1), dim3(RB), 0, stream, pnum, pden,
                     out);
}

// Round 3
// 87.535 us; speedup vs baseline: 1.0358x; 1.0358x over previous
//
#include <hip/hip_runtime.h>
#include <math.h>

// Problem constants (fixed by the reference setup_inputs)
constexpr int B = 4;
constexpr int N = 8192;
constexpr int M = 8192;
constexpr int NPTS = B * N;   // 32768 xyz1 points
constexpr int MPTS = B * M;   // 32768 xyz2 points

constexpr int TPB = 256;                  // threads per block (main)
constexpr int PB  = 16;                   // xyz1 points per thread
constexpr int PTS_PER_BLOCK = TPB * PB;   // 4096
constexpr int NB1 = N / PTS_PER_BLOCK;    // 2 point-blocks per batch
constexpr int MC  = 64;                   // chunks over M
constexpr int CHUNK = M / MC;             // 128 xyz2 points per chunk

constexpr int RBLOCKS = NPTS / TPB;       // 128 reduce blocks

typedef float v2f __attribute__((ext_vector_type(2)));

// ---------------------------------------------------------------------------
// Kernel 1: main O(N*M) min. Block = (mc, pb, b), grid = 64*2*4 = 512 blocks
// = exactly 2 blocks/CU (8 waves/CU). Stages its q-chunk
// (-2x,-2y,-2z,|p|^2) into LDS SoA arrays; inner loop per xyz1-point per
// 2 q-points: 3 v_pk_fma_f32 + 1 v_min3_f32 = 2.0 VALU instr/pair.
// Writes per-chunk partial min-d2 with pure coalesced stores (no atomics,
// no init required — every slot is written). Thread (0,0,0) also zeroes the
// accumulators/counter consumed by kernel 2 (stream-ordered, safe).
// ---------------------------------------------------------------------------
__global__ __launch_bounds__(TPB, 2) void chamfer_min_kernel(
    const float* __restrict__ xyz1, const float* __restrict__ xyz2,
    float* __restrict__ part, float* __restrict__ acc,
    unsigned* __restrict__ counter) {
  __shared__ float lqx[CHUNK], lqy[CHUNK], lqz[CHUNK], lqw[CHUNK];

  const int t  = threadIdx.x;
  const int mc = blockIdx.x;  // M-chunk      0..MC-1
  const int pb = blockIdx.y;  // point-block  0..NB1-1
  const int b  = blockIdx.z;  // batch        0..B-1

  if (mc == 0 && pb == 0 && b == 0 && t == 0) {
    acc[0] = 0.0f;
    acc[1] = 0.0f;
    counter[0] = 0u;
  }

  // Stage q chunk: thread k (k < CHUNK) computes one xyz2 point.
  if (t < CHUNK) {
    int gi = b * M + mc * CHUNK + t;
    float x = xyz2[3 * gi + 0];
    float y = xyz2[3 * gi + 1];
    float z = xyz2[3 * gi + 2];
    lqx[t] = -2.0f * x;
    lqy[t] = -2.0f * y;
    lqz[t] = -2.0f * z;
    lqw[t] = fmaf(x, x, fmaf(y, y, z * z));
  }

  // Load this thread's PB xyz1 points (broadcast pairs for the packed FMA)
  v2f x2[PB], y2[PB], z2[PB];
  float smin[PB];
  const int base1 = b * N + pb * PTS_PER_BLOCK + t;
#pragma unroll
  for (int p = 0; p < PB; ++p) {
    int idx = base1 + p * TPB;
    float x = xyz1[3 * idx + 0];
    float y = xyz1[3 * idx + 1];
    float z = xyz1[3 * idx + 2];
    x2[p] = (v2f){x, x};
    y2[p] = (v2f){y, y};
    z2[p] = (v2f){z, z};
    smin[p] = INFINITY;
  }
  __syncthreads();

  // Inner loop: 4 q-points per iteration (one broadcast ds_read_b128 per
  // component — all lanes same address, conflict-free), two packed j-pairs.
#pragma unroll 4
  for (int j4 = 0; j4 < CHUNK / 4; ++j4) {
    float4 vx = *(const float4*)&lqx[4 * j4];
    float4 vy = *(const float4*)&lqy[4 * j4];
    float4 vz = *(const float4*)&lqz[4 * j4];
    float4 vw = *(const float4*)&lqw[4 * j4];

    v2f qx0 = (v2f){vx.x, vx.y}, qx1 = (v2f){vx.z, vx.w};
    v2f qy0 = (v2f){vy.x, vy.y}, qy1 = (v2f){vy.z, vy.w};
    v2f qz0 = (v2f){vz.x, vz.y}, qz1 = (v2f){vz.z, vz.w};
    v2f qw0 = (v2f){vw.x, vw.y}, qw1 = (v2f){vw.z, vw.w};

#pragma unroll
    for (int p = 0; p < PB; ++p) {
      v2f s0 = __builtin_elementwise_fma(
          x2[p], qx0,
          __builtin_elementwise_fma(
              y2[p], qy0, __builtin_elementwise_fma(z2[p], qz0, qw0)));
      smin[p] = fminf(fminf(s0.x, s0.y), smin[p]);  // -> v_min3_f32
      v2f s1 = __builtin_elementwise_fma(
          x2[p], qx1,
          __builtin_elementwise_fma(
              y2[p], qy1, __builtin_elementwise_fma(z2[p], qz1, qw1)));
      smin[p] = fminf(fminf(s1.x, s1.y), smin[p]);
    }
  }

  // Epilogue: d2 = max(|p1|^2 + smin, 0); coalesced partial store.
#pragma unroll
  for (int p = 0; p < PB; ++p) {
    int idx = base1 + p * TPB;
    float x = x2[p].x, y = y2[p].x, z = z2[p].x;
    float n2 = fmaf(x, x, fmaf(y, y, z * z));
    part[(size_t)mc * NPTS + idx] = fmaxf(n2 + smin[p], 0.0f);
  }
}

// ---------------------------------------------------------------------------
// Kernel 2 (fused reduce + finalize): per point min over MC chunk partials,
// sqrt, weight, wave+block reduce, device atomicAdd of (sum d*w, sum w);
// the last block to finish (atomic counter) reads the totals back via
// RMW-with-0 and writes the final quotient.
// ---------------------------------------------------------------------------
__global__ __launch_bounds__(TPB) void reduce_finalize_kernel(
    const float* __restrict__ part, const float* __restrict__ w,
    float* __restrict__ acc, unsigned* __restrict__ counter,
    float* __restrict__ out) {
  const int i = blockIdx.x * TPB + threadIdx.x;  // point 0..NPTS-1

  // 8-way ILP partial mins over the MC strided (coalesced) loads
  float m[8];
#pragma unroll
  for (int k = 0; k < 8; ++k) m[k] = INFINITY;
#pragma unroll
  for (int mc = 0; mc < MC; mc += 8) {
#pragma unroll
    for (int k = 0; k < 8; ++k)
      m[k] = fminf(m[k], part[(size_t)(mc + k) * NPTS + i]);
  }
  float d2 = fminf(fminf(fminf(m[0], m[1]), fminf(m[2], m[3])),
                   fminf(fminf(m[4], m[5]), fminf(m[6], m[7])));
  float d  = sqrtf(d2);
  float wi = w[i];
  float num = d * wi;
  float den = wi;

#pragma unroll
  for (int off = 32; off > 0; off >>= 1) {
    num += __shfl_down(num, off, 64);
    den += __shfl_down(den, off, 64);
  }

  __shared__ float snum[TPB / 64], sden[TPB / 64];
  const int wid  = threadIdx.x >> 6;
  const int lane = threadIdx.x & 63;
  if (lane == 0) { snum[wid] = num; sden[wid] = den; }
  __syncthreads();

  if (threadIdx.x == 0) {
    float a = 0.0f, c = 0.0f;
#pragma unroll
    for (int k = 0; k < TPB / 64; ++k) { a += snum[k]; c += sden[k]; }
    atomicAdd(&acc[0], a);
    atomicAdd(&acc[1], c);
    __threadfence();
    unsigned prev = atomicAdd(counter, 1u);
    if (prev == (unsigned)(gridDim.x - 1)) {
      // Last block: totals are complete; read back via device-scope RMW.
      float ta = atomicAdd(&acc[0], 0.0f);
      float tc = atomicAdd(&acc[1], 0.0f);
      out[0] = ta / tc;
    }
  }
}

// ---------------------------------------------------------------------------
extern "C" void kernel_launch(void* const* d_in, const int* in_sizes, int n_in,
                              void* d_out, int out_size, void* d_ws,
                              size_t ws_size, hipStream_t stream) {
  const float* xyz1 = (const float*)d_in[0];  // [B,N,3]
  const float* xyz2 = (const float*)d_in[1];  // [B,M,3]
  const float* wts  = (const float*)d_in[2];  // [B,N]
  float* out = (float*)d_out;

  char* ws = (char*)d_ws;
  float*    part    = (float*)ws;  // MC * NPTS floats = 8 MB
  float*    acc     = (float*)(ws + (size_t)MC * NPTS * sizeof(float));
  unsigned* counter = (unsigned*)(acc + 2);

  hipLaunchKernelGGL(chamfer_min_kernel, dim3(MC, NB1, B), dim3(TPB), 0,
                     stream, xyz1, xyz2, part, acc, counter);
  hipLaunchKernelGGL(reduce_finalize_kernel, dim3(RBLOCKS), dim3(TPB), 0,
                     stream, part, wts, acc, counter, out);
}

// Round 4
// 85.838 us; speedup vs baseline: 1.0563x; 1.0198x over previous
//
#include <hip/hip_runtime.h>
#include <math.h>

// Problem constants (fixed by the reference setup_inputs)
constexpr int B = 4;
constexpr int N = 8192;
constexpr int M = 8192;
constexpr int NPTS = B * N;   // 32768 xyz1 points
constexpr int MPTS = B * M;   // 32768 xyz2 points

constexpr int TPB = 256;                  // threads per block (main)
constexpr int PB  = 8;                    // xyz1 points per thread
constexpr int PTS_PER_BLOCK = TPB * PB;   // 2048
constexpr int NB1 = N / PTS_PER_BLOCK;    // 4 point-blocks per batch
constexpr int MC  = 32;                   // chunks over M
constexpr int CHUNK = M / MC;             // 256 xyz2 points per chunk (== TPB)

constexpr int RBLOCKS = NPTS / TPB;       // 128 reduce blocks

typedef float v2f __attribute__((ext_vector_type(2)));

// ---------------------------------------------------------------------------
// Kernel 1: main O(N*M) min. Block = (mc, pb, b), grid = 32*4*4 = 512 blocks
// = exactly 2 blocks/CU (8 waves/CU, 2/SIMD). Stages its q-chunk
// (-2x,-2y,-2z,|p|^2) into LDS SoA arrays (broadcast ds_read_b128,
// conflict-free); inner loop per xyz1-point per 2 q-points:
// 3 v_pk_fma_f32 + 1 v_min3_f32 = 2.0 VALU instr/pair -> 6.8 us device floor.
// Writes per-chunk partial min-d2 with pure coalesced stores (no atomics, no
// init). Thread (0,0,0) zeroes the accumulators/counter for kernel 2.
// ---------------------------------------------------------------------------
__global__ __launch_bounds__(TPB, 2) void chamfer_min_kernel(
    const float* __restrict__ xyz1, const float* __restrict__ xyz2,
    float* __restrict__ part, float* __restrict__ acc,
    unsigned* __restrict__ counter) {
  __shared__ float lqx[CHUNK], lqy[CHUNK], lqz[CHUNK], lqw[CHUNK];

  const int t  = threadIdx.x;
  const int mc = blockIdx.x;  // M-chunk      0..MC-1
  const int pb = blockIdx.y;  // point-block  0..NB1-1
  const int b  = blockIdx.z;  // batch        0..B-1

  if (mc == 0 && pb == 0 && b == 0 && t == 0) {
    acc[0] = 0.0f;
    acc[1] = 0.0f;
    counter[0] = 0u;
  }

  // Stage q chunk: CHUNK == TPB, one xyz2 point per thread.
  {
    int gi = b * M + mc * CHUNK + t;
    float x = xyz2[3 * gi + 0];
    float y = xyz2[3 * gi + 1];
    float z = xyz2[3 * gi + 2];
    lqx[t] = -2.0f * x;
    lqy[t] = -2.0f * y;
    lqz[t] = -2.0f * z;
    lqw[t] = fmaf(x, x, fmaf(y, y, z * z));
  }

  // This thread's PB xyz1 points as broadcast pairs for the packed FMA.
  v2f x2[PB], y2[PB], z2[PB];
  float smin[PB];
  const int base1 = b * N + pb * PTS_PER_BLOCK + t;
#pragma unroll
  for (int p = 0; p < PB; ++p) {
    int idx = base1 + p * TPB;
    float x = xyz1[3 * idx + 0];
    float y = xyz1[3 * idx + 1];
    float z = xyz1[3 * idx + 2];
    x2[p] = (v2f){x, x};
    y2[p] = (v2f){y, y};
    z2[p] = (v2f){z, z};
    smin[p] = INFINITY;
  }
  __syncthreads();

  // 4 q-points per iteration: one broadcast ds_read_b128 per component
  // (4 reads amortized over PB*8 = 64 VALU instrs), two packed j-pairs.
#pragma unroll 2
  for (int j4 = 0; j4 < CHUNK / 4; ++j4) {
    float4 vx = *(const float4*)&lqx[4 * j4];
    float4 vy = *(const float4*)&lqy[4 * j4];
    float4 vz = *(const float4*)&lqz[4 * j4];
    float4 vw = *(const float4*)&lqw[4 * j4];

    v2f qx0 = (v2f){vx.x, vx.y}, qx1 = (v2f){vx.z, vx.w};
    v2f qy0 = (v2f){vy.x, vy.y}, qy1 = (v2f){vy.z, vy.w};
    v2f qz0 = (v2f){vz.x, vz.y}, qz1 = (v2f){vz.z, vz.w};
    v2f qw0 = (v2f){vw.x, vw.y}, qw1 = (v2f){vw.z, vw.w};

#pragma unroll
    for (int p = 0; p < PB; ++p) {
      v2f s0 = __builtin_elementwise_fma(
          x2[p], qx0,
          __builtin_elementwise_fma(
              y2[p], qy0, __builtin_elementwise_fma(z2[p], qz0, qw0)));
      smin[p] = fminf(fminf(s0.x, s0.y), smin[p]);  // -> v_min3_f32
      v2f s1 = __builtin_elementwise_fma(
          x2[p], qx1,
          __builtin_elementwise_fma(
              y2[p], qy1, __builtin_elementwise_fma(z2[p], qz1, qw1)));
      smin[p] = fminf(fminf(s1.x, s1.y), smin[p]);
    }
  }

  // Epilogue: d2 = max(|p1|^2 + smin, 0); coalesced partial store.
#pragma unroll
  for (int p = 0; p < PB; ++p) {
    int idx = base1 + p * TPB;
    float x = x2[p].x, y = y2[p].x, z = z2[p].x;
    float n2 = fmaf(x, x, fmaf(y, y, z * z));
    part[(size_t)mc * NPTS + idx] = fmaxf(n2 + smin[p], 0.0f);
  }
}

// ---------------------------------------------------------------------------
// Kernel 2 (fused reduce + finalize): per point min over MC chunk partials,
// sqrt, weight, wave+block reduce, device atomicAdd of (sum d*w, sum w);
// last block (atomic counter) reads totals via RMW and writes the quotient.
// ---------------------------------------------------------------------------
__global__ __launch_bounds__(TPB) void reduce_finalize_kernel(
    const float* __restrict__ part, const float* __restrict__ w,
    float* __restrict__ acc, unsigned* __restrict__ counter,
    float* __restrict__ out) {
  const int i = blockIdx.x * TPB + threadIdx.x;  // point 0..NPTS-1

  // 8-way ILP partial mins over the MC strided (coalesced) loads
  float m[8];
#pragma unroll
  for (int k = 0; k < 8; ++k) m[k] = INFINITY;
#pragma unroll
  for (int mc = 0; mc < MC; mc += 8) {
#pragma unroll
    for (int k = 0; k < 8; ++k)
      m[k] = fminf(m[k], part[(size_t)(mc + k) * NPTS + i]);
  }
  float d2 = fminf(fminf(fminf(m[0], m[1]), fminf(m[2], m[3])),
                   fminf(fminf(m[4], m[5]), fminf(m[6], m[7])));
  float d  = sqrtf(d2);
  float wi = w[i];
  float num = d * wi;
  float den = wi;

#pragma unroll
  for (int off = 32; off > 0; off >>= 1) {
    num += __shfl_down(num, off, 64);
    den += __shfl_down(den, off, 64);
  }

  __shared__ float snum[TPB / 64], sden[TPB / 64];
  const int wid  = threadIdx.x >> 6;
  const int lane = threadIdx.x & 63;
  if (lane == 0) { snum[wid] = num; sden[wid] = den; }
  __syncthreads();

  if (threadIdx.x == 0) {
    float a = 0.0f, c = 0.0f;
#pragma unroll
    for (int k = 0; k < TPB / 64; ++k) { a += snum[k]; c += sden[k]; }
    atomicAdd(&acc[0], a);
    atomicAdd(&acc[1], c);
    __threadfence();
    unsigned prev = atomicAdd(counter, 1u);
    if (prev == (unsigned)(gridDim.x - 1)) {
      float ta = atomicAdd(&acc[0], 0.0f);
      float tc = atomicAdd(&acc[1], 0.0f);
      out[0] = ta / tc;
    }
  }
}

// ---------------------------------------------------------------------------
extern "C" void kernel_launch(void* const* d_in, const int* in_sizes, int n_in,
                              void* d_out, int out_size, void* d_ws,
                              size_t ws_size, hipStream_t stream) {
  const float* xyz1 = (const float*)d_in[0];  // [B,N,3]
  const float* xyz2 = (const float*)d_in[1];  // [B,M,3]
  const float* wts  = (const float*)d_in[2];  // [B,N]
  float* out = (float*)d_out;

  char* ws = (char*)d_ws;
  float*    part    = (float*)ws;  // MC * NPTS floats = 4 MB
  float*    acc     = (float*)(ws + (size_t)MC * NPTS * sizeof(float));
  unsigned* counter = (unsigned*)(acc + 2);

  hipLaunchKernelGGL(chamfer_min_kernel, dim3(MC, NB1, B), dim3(TPB), 0,
                     stream, xyz1, xyz2, part, acc, counter);
  hipLaunchKernelGGL(reduce_finalize_kernel, dim3(RBLOCKS), dim3(TPB), 0,
                     stream, part, wts, acc, counter, out);
}